// Round 8
// baseline (19.473 us; speedup 1.0000x reference)
//
#include <hip/hip_runtime.h>
#include <math.h>

#define NB 4
#define CC 128
#define HW 784        // 28*28
#define KK 64
#define DD 512
#define TD 8          // d-rows per block
#define PXB 392       // pixels per block (half of 784)
#define CH 64         // channels per c-half
#define BLK 832       // 13 waves: 2 x 392 active threads (+ pad)

// K1: block = (n, 8-d-group, pixel-half). Threads are (pixel, c-half) pairs:
//   t < 416: c in [0,64), pixel p0 + t;  t >= 416: c in [64,128), pixel p0 + (t-416).
//   Each thread: 64 coalesced x loads + sumsq + 8 dot-FMAs per c.
//   Halves combined in LDS -> feat = (dotL+dotH)*rinv + bias.
//   |feat| <= ~0.8 (normalized x dot small w row) so softmax needs NO max pass:
//   each block emits partial (s = sum e^f, ws = sum f*e^f) over its 392 pixels.
// 26 waves/CU (vs 13) at IDENTICAL VMEM-instruction count and L2 traffic —
// pure latency-hiding occupancy doubling.
__global__ __launch_bounds__(BLK, 7) void netvlad_gemm_partial(
    const float* __restrict__ x, const float* __restrict__ w,
    const float* __restrict__ b, float2* __restrict__ pws)
{
    __shared__ float w_s[CC][TD];       // 4 KB transposed [c][j]
    __shared__ float feat_s[TD][PXB];   // 12.25 KB
    __shared__ float sq_s[PXB];         // 1.5 KB

    const int tid = threadIdx.x;
    const int bb  = blockIdx.x;
    const int n   = bb >> 7;
    const int dg  = (bb >> 1) & 63;
    const int h   = bb & 1;
    const int d0  = dg * TD;
    const int p0  = h * PXB;

    // stage the full 128x8 weight tile transposed
    for (int i = tid; i < CC * TD; i += BLK) {
        int c = i >> 3, j = i & 7;
        w_s[c][j] = w[(size_t)(d0 + j) * CC + c];
    }

    const int  ch    = (tid >= 416) ? 1 : 0;
    const int  praw  = tid - ch * 416;
    const bool act   = praw < PXB;
    const int  p_loc = act ? praw : 0;   // clamp: keeps loads in-bounds
    const int  cb    = ch * CH;

    __syncthreads();

    const float* xp = x + (size_t)n * CC * HW + (size_t)cb * HW + (p0 + p_loc);

    float acc[TD];
    #pragma unroll
    for (int j = 0; j < TD; ++j) acc[j] = 0.f;
    float sq = 0.f;

    #pragma unroll 8
    for (int c = 0; c < CH; ++c) {
        float xv = xp[(size_t)c * HW];                 // coalesced dword
        float4 wlo = *(const float4*)&w_s[cb + c][0];  // <=2 distinct addrs/wave
        float4 whi = *(const float4*)&w_s[cb + c][4];
        sq = fmaf(xv, xv, sq);
        acc[0] = fmaf(wlo.x, xv, acc[0]);
        acc[1] = fmaf(wlo.y, xv, acc[1]);
        acc[2] = fmaf(wlo.z, xv, acc[2]);
        acc[3] = fmaf(wlo.w, xv, acc[3]);
        acc[4] = fmaf(whi.x, xv, acc[4]);
        acc[5] = fmaf(whi.y, xv, acc[5]);
        acc[6] = fmaf(whi.z, xv, acc[6]);
        acc[7] = fmaf(whi.w, xv, acc[7]);
    }

    // combine the two c-halves through LDS
    if (act && ch == 0) {
        sq_s[p_loc] = sq;
        #pragma unroll
        for (int j = 0; j < TD; ++j) feat_s[j][p_loc] = acc[j];
    }
    __syncthreads();
    if (act && ch == 1) {
        float r = 1.0f / fmaxf(sqrtf(sq_s[p_loc] + sq), 1e-12f);
        #pragma unroll
        for (int j = 0; j < TD; ++j)
            feat_s[j][p_loc] = fmaf(feat_s[j][p_loc] + acc[j], r, b[d0 + j]);
    }
    __syncthreads();

    // partial softmax sums over this block's 392 pixels (no max subtraction:
    // |feat| bounded by ~0.8, exp is safe; shift-invariance => same result)
    const int lane = tid & 63;
    const int wave = tid >> 6;
    if (wave < TD) {
        const int j = wave;
        float s = 0.f, ws = 0.f;
        for (int q = lane; q < PXB; q += 64) {
            float f = feat_s[j][q];
            float e = __expf(f);
            s += e;
            ws = fmaf(e, f, ws);
        }
        #pragma unroll
        for (int off = 32; off; off >>= 1) {
            s  += __shfl_xor(s, off, 64);
            ws += __shfl_xor(ws, off, 64);
        }
        if (lane == 0)
            pws[(size_t)(n * DD + d0 + j) * 2 + h] = make_float2(s, ws);
    }
}

// K2: merge the two pixel-half partials per (n,d) row, divide, broadcast over k.
// grid = 32 blocks x 512 threads; thread d handles row (n,d), writes 8 k-slots.
__global__ __launch_bounds__(512) void netvlad_finalize(
    const float2* __restrict__ pws, float* __restrict__ out)
{
    const int d  = threadIdx.x;
    const int n  = blockIdx.x >> 3;
    const int ks = (blockIdx.x & 7) * 8;
    float2 a = pws[(size_t)(n * DD + d) * 2 + 0];
    float2 c = pws[(size_t)(n * DD + d) * 2 + 1];
    float g = (a.y + c.y) / (a.x + c.x);
    #pragma unroll
    for (int i = 0; i < 8; ++i)
        out[(size_t)n * KK * DD + (size_t)(ks + i) * DD + d] = g;  // coalesced
}

extern "C" void kernel_launch(void* const* d_in, const int* in_sizes, int n_in,
                              void* d_out, int out_size, void* d_ws, size_t ws_size,
                              hipStream_t stream) {
    const float* x = (const float*)d_in[0];   // (4,128,28,28)
    const float* w = (const float*)d_in[1];   // (512,128)
    const float* b = (const float*)d_in[2];   // (512,)
    // d_in[3] = centroids (64,512): provably unused — softmax over the spatial
    // axis is invariant to the per-(k,d) constant shift, so vlad[n,k,d] is
    // identical for all k.
    float2* pws = (float2*)d_ws;              // 4096 float2 = 32 KB partials
    float* out  = (float*)d_out;              // (4,64,512) fp32

    netvlad_gemm_partial<<<NB * (DD / TD) * 2, BLK, 0, stream>>>(x, w, b, pws);
    netvlad_finalize<<<32, 512, 0, stream>>>(pws, out);
}

// Round 9
// 17.568 us; speedup vs baseline: 1.1084x; 1.1084x over previous
//
#include <hip/hip_runtime.h>
#include <math.h>

#define NB 4
#define CC 128
#define HW 784        // 28*28
#define KK 64
#define DD 512
#define TD 8          // d-rows per block
#define BLK 832       // 13 waves; >= HW so each thread owns <=1 pixel
#define UNR 16        // x-load batch width (outstanding loads per wave)

// Single fused kernel, one block per (n, 8-d-row group), 13 waves.
// R4 structure (best: 17.52 us) + deeper memory pipelining: the c-loop issues
// 16 independent x loads per batch before consuming them, doubling per-wave
// outstanding loads (8 -> 16) to cover the ~200-340 cyc L2 hit latency.
//   - thread t owns pixel p=t (t<784): streams x[n,:,p], accumulating the
//     8 conv dot-products AND the per-pixel sum-of-squares in one pass
//   - weights staged transposed in LDS, read as 2 broadcast ds_read_b128
//   - feat = rinv*dot + bias staged in LDS
//   - waves 0..7 each do one row's softmax-weighted mean over P=784
//   - vlad[n,k,d] is k-independent (softmax over the spatial axis is invariant
//     to the per-(k,d) centroid shift) -> broadcast write via LDS
__global__ __launch_bounds__(BLK) void netvlad_fused_kernel(
    const float* __restrict__ x, const float* __restrict__ w,
    const float* __restrict__ b, float* __restrict__ out)
{
    __shared__ float w_s[CC][TD];        // 4 KB, transposed: [c][j]
    __shared__ float feat_s[TD][HW];     // 25 KB
    __shared__ float g_s[TD];

    const int tid = threadIdx.x;
    const int n  = blockIdx.x >> 6;      // 64 d-groups per n
    const int d0 = (blockIdx.x & 63) * TD;
    const bool act = tid < HW;

    // stage the 8x128 weight tile transposed (one-time, 4 KB)
    for (int i = tid; i < CC * TD; i += BLK) {
        int c = i >> 3, j = i & 7;
        w_s[c][j] = w[(size_t)(d0 + j) * CC + c];
    }
    __syncthreads();

    if (act) {
        const float* xp = x + (size_t)n * CC * HW + tid;
        float acc[TD];
        #pragma unroll
        for (int j = 0; j < TD; ++j) acc[j] = 0.f;
        float sq = 0.f;

        // 16-deep software pipeline: issue 16 independent loads, then consume.
        for (int cc = 0; cc < CC; cc += UNR) {
            float xv[UNR];
            #pragma unroll
            for (int u = 0; u < UNR; ++u)
                xv[u] = xp[(size_t)(cc + u) * HW];     // 16 loads in flight
            #pragma unroll
            for (int u = 0; u < UNR; ++u) {
                const int c = cc + u;
                float4 wlo = *(const float4*)&w_s[c][0];   // broadcast b128
                float4 whi = *(const float4*)&w_s[c][4];   // broadcast b128
                float xvu = xv[u];
                sq = fmaf(xvu, xvu, sq);
                acc[0] = fmaf(wlo.x, xvu, acc[0]);
                acc[1] = fmaf(wlo.y, xvu, acc[1]);
                acc[2] = fmaf(wlo.z, xvu, acc[2]);
                acc[3] = fmaf(wlo.w, xvu, acc[3]);
                acc[4] = fmaf(whi.x, xvu, acc[4]);
                acc[5] = fmaf(whi.y, xvu, acc[5]);
                acc[6] = fmaf(whi.z, xvu, acc[6]);
                acc[7] = fmaf(whi.w, xvu, acc[7]);
            }
        }

        float r = 1.0f / fmaxf(sqrtf(sq), 1e-12f);
        #pragma unroll
        for (int j = 0; j < TD; ++j)
            feat_s[j][tid] = fmaf(acc[j], r, b[d0 + j]);
    }
    __syncthreads();

    // Per-row softmax-weighted mean over P=784; wave j (j<8) handles row j.
    const int lane = tid & 63;
    const int wave = tid >> 6;
    if (wave < TD) {
        const int j = wave;
        float m = -INFINITY;
        for (int q = lane; q < HW; q += 64) m = fmaxf(m, feat_s[j][q]);
        #pragma unroll
        for (int off = 32; off; off >>= 1) m = fmaxf(m, __shfl_xor(m, off, 64));
        float s = 0.f, ws = 0.f;
        for (int q = lane; q < HW; q += 64) {
            float f = feat_s[j][q];
            float e = __expf(f - m);
            s += e;
            ws = fmaf(e, f, ws);
        }
        #pragma unroll
        for (int off = 32; off; off >>= 1) {
            s  += __shfl_xor(s, off, 64);
            ws += __shfl_xor(ws, off, 64);
        }
        if (lane == 0) g_s[j] = ws / s;
    }
    __syncthreads();

    // Broadcast across k with a coalesced write: block owns out[n, :, d0:d0+8]
    if (tid < KK * TD) {
        int k = tid >> 3, j = tid & 7;
        out[(size_t)n * KK * DD + (size_t)k * DD + d0 + j] = g_s[j];
    }
}

extern "C" void kernel_launch(void* const* d_in, const int* in_sizes, int n_in,
                              void* d_out, int out_size, void* d_ws, size_t ws_size,
                              hipStream_t stream) {
    const float* x = (const float*)d_in[0];   // (4,128,28,28)
    const float* w = (const float*)d_in[1];   // (512,128)
    const float* b = (const float*)d_in[2];   // (512,)
    // d_in[3] = centroids (64,512): provably unused — softmax over the spatial
    // axis is invariant to the per-(k,d) constant shift, so vlad[n,k,d] is
    // identical for all k.
    float* out = (float*)d_out;               // (4,64,512) fp32

    netvlad_fused_kernel<<<NB * (DD / TD), BLK, 0, stream>>>(x, w, b, out);
}